// Round 1
// baseline (478.552 us; speedup 1.0000x reference)
//
#include <hip/hip_runtime.h>

// Fused WeightedMAE + Patch-SSIM loss for (8,8,512,512) fp32 inputs.
// One block per (patch, channel): 512 patches x 8 channels = 4096 blocks.
// Phase A: load 64x64 tile (x = in+out, y = tgt) into LDS, fuse MAE partials.
// Phase B: horizontal 11-tap separable gaussian conv of {x,y,x^2,y^2,xy}.
// Phase C: vertical 11-tap conv (4col x 3row register blocks) + SSIM formula.
// Reduction: wave shuffle -> LDS -> atomicAdd to d_ws; tiny finalize kernel.

#define C1c 1.0e-4f
#define C2c 9.0e-4f

__global__ __launch_bounds__(512)
void fused_loss_kernel(const float* __restrict__ in,
                       const float* __restrict__ outp,
                       const float* __restrict__ tgt,
                       float* __restrict__ ws) {
    __shared__ float xt[64][80];          // padded: cols 64..79 zero
    __shared__ float yt[64][80];
    __shared__ float Hq[5][64][56];       // horizontal conv results
    __shared__ float red[8][3];

    const int tid = threadIdx.x;
    const int pc  = blockIdx.x;           // 0..4095
    const int ch  = pc & 7;
    const int p   = pc >> 3;              // 0..511
    const int b   = p >> 6;
    const int ph  = (p >> 3) & 7;
    const int pw  = p & 7;

    // gaussian weights (match np.float32 pipeline closely enough)
    float wgt[11];
    {
        float s = 0.0f;
#pragma unroll
        for (int j = 0; j < 11; ++j) {
            float d = (float)(j - 5);
            wgt[j] = expf(-d * d / 4.5f);
            s += wgt[j];
        }
        float invs = 1.0f / s;
#pragma unroll
        for (int j = 0; j < 11; ++j) wgt[j] *= invs;
    }

    // ---------------- Phase A: load tile + MAE ----------------
    float mae_num = 0.0f, mae_den = 0.0f;
    const size_t img_base =
        ((size_t)(b * 8 + ch) * 512 + (size_t)(ph * 64)) * 512 + (size_t)(pw * 64);

#pragma unroll
    for (int i = 0; i < 2; ++i) {
        const int pos = tid + i * 512;        // 0..1023 float4 positions
        const int r   = pos >> 4;             // 0..63
        const int c4  = (pos & 15) << 2;      // 0..60
        const size_t off = img_base + (size_t)r * 512 + (size_t)c4;
        const float4 iv = *(const float4*)(in   + off);
        const float4 ov = *(const float4*)(outp + off);
        const float4 tv = *(const float4*)(tgt  + off);
        float4 xv;
        xv.x = iv.x + ov.x; xv.y = iv.y + ov.y;
        xv.z = iv.z + ov.z; xv.w = iv.w + ov.w;
        *(float4*)&xt[r][c4] = xv;
        *(float4*)&yt[r][c4] = tv;
        // MAE: hp = tgt - in; w = |hp|>0; num += w*|out - hp|
        {
            float hp;
            hp = tv.x - iv.x; if (fabsf(hp) > 0.0f) { mae_den += 1.0f; mae_num += fabsf(ov.x - hp); }
            hp = tv.y - iv.y; if (fabsf(hp) > 0.0f) { mae_den += 1.0f; mae_num += fabsf(ov.y - hp); }
            hp = tv.z - iv.z; if (fabsf(hp) > 0.0f) { mae_den += 1.0f; mae_num += fabsf(ov.z - hp); }
            hp = tv.w - iv.w; if (fabsf(hp) > 0.0f) { mae_den += 1.0f; mae_num += fabsf(ov.w - hp); }
        }
    }
    // zero-fill padding columns 64..79
    if (tid < 256) {
        const int r   = tid >> 2;
        const int cpi = tid & 3;
        const float4 z = make_float4(0.f, 0.f, 0.f, 0.f);
        *(float4*)&xt[r][64 + cpi * 4] = z;
        *(float4*)&yt[r][64 + cpi * 4] = z;
    }
    __syncthreads();

    // ---------------- Phase B: horizontal conv ----------------
    // 64 rows x 16 col-chunks (4 outputs each) = 1024 chunks; 2 per thread.
#pragma unroll
    for (int it = 0; it < 2; ++it) {
        const int chunk = tid + it * 512;
        const int row = chunk >> 4;
        const int cc  = chunk & 15;
        const int c0  = cc << 2;          // 0..60
        float xs[16], ys[16];
#pragma unroll
        for (int v = 0; v < 4; ++v) {
            const float4 x4 = *(const float4*)&xt[row][c0 + 4 * v];
            const float4 y4 = *(const float4*)&yt[row][c0 + 4 * v];
            xs[4*v+0] = x4.x; xs[4*v+1] = x4.y; xs[4*v+2] = x4.z; xs[4*v+3] = x4.w;
            ys[4*v+0] = y4.x; ys[4*v+1] = y4.y; ys[4*v+2] = y4.z; ys[4*v+3] = y4.w;
        }
        float s0[4] = {0,0,0,0}, s1[4] = {0,0,0,0}, s2[4] = {0,0,0,0};
        float s3[4] = {0,0,0,0}, s4[4] = {0,0,0,0};
#pragma unroll
        for (int j = 0; j < 11; ++j) {
            const float w = wgt[j];
#pragma unroll
            for (int o = 0; o < 4; ++o) {
                const float xv = xs[o + j];
                const float yv = ys[o + j];
                const float tx = w * xv;
                const float ty = w * yv;
                s0[o] += tx;
                s1[o] += ty;
                s2[o] = fmaf(tx, xv, s2[o]);
                s3[o] = fmaf(ty, yv, s3[o]);
                s4[o] = fmaf(tx, yv, s4[o]);
            }
        }
        if (c0 < 56) {
            *(float4*)&Hq[0][row][c0] = make_float4(s0[0], s0[1], s0[2], s0[3]);
            *(float4*)&Hq[1][row][c0] = make_float4(s1[0], s1[1], s1[2], s1[3]);
            *(float4*)&Hq[2][row][c0] = make_float4(s2[0], s2[1], s2[2], s2[3]);
            *(float4*)&Hq[3][row][c0] = make_float4(s3[0], s3[1], s3[2], s3[3]);
            *(float4*)&Hq[4][row][c0] = make_float4(s4[0], s4[1], s4[2], s4[3]);
        }
    }
    __syncthreads();

    // ---------------- Phase C: vertical conv + SSIM ----------------
    // 18 row-chunks (3 rows each) x 16 col-chunks (4 cols) = 288 chunks
    float ssim_acc = 0.0f;
    if (tid < 288) {
        const int vrc = tid >> 4;     // 0..17
        const int cc  = tid & 15;     // 0..15
        if (cc < 14) {
            const int c0  = cc << 2;  // 0..52
            const int vr0 = vrc * 3;  // 0..51
            float acc[3][5][4];
#pragma unroll
            for (int i = 0; i < 3; ++i)
#pragma unroll
                for (int q = 0; q < 5; ++q)
#pragma unroll
                    for (int k = 0; k < 4; ++k) acc[i][q][k] = 0.0f;
#pragma unroll
            for (int hr = 0; hr < 13; ++hr) {
                float h[5][4];
#pragma unroll
                for (int q = 0; q < 5; ++q) {
                    const float4 t = *(const float4*)&Hq[q][vr0 + hr][c0];
                    h[q][0] = t.x; h[q][1] = t.y; h[q][2] = t.z; h[q][3] = t.w;
                }
#pragma unroll
                for (int i = 0; i < 3; ++i) {
                    const int j = hr - i;
                    if (j >= 0 && j <= 10) {
                        const float w = wgt[j];
#pragma unroll
                        for (int q = 0; q < 5; ++q)
#pragma unroll
                            for (int k = 0; k < 4; ++k)
                                acc[i][q][k] = fmaf(w, h[q][k], acc[i][q][k]);
                    }
                }
            }
#pragma unroll
            for (int i = 0; i < 3; ++i) {
#pragma unroll
                for (int k = 0; k < 4; ++k) {
                    if (c0 + k < 54) {
                        const float mu1 = acc[i][0][k], mu2 = acc[i][1][k];
                        const float sxx = acc[i][2][k], syy = acc[i][3][k], sxy = acc[i][4][k];
                        const float mu1sq = mu1 * mu1;
                        const float mu2sq = mu2 * mu2;
                        const float mu12  = mu1 * mu2;
                        const float num = (2.0f * mu12 + C1c) * (2.0f * (sxy - mu12) + C2c);
                        const float den = (mu1sq + mu2sq + C1c) *
                                          ((sxx - mu1sq) + (syy - mu2sq) + C2c);
                        ssim_acc += num / den;
                    }
                }
            }
        }
    }

    // ---------------- Reduction ----------------
    float v0 = mae_num, v1 = mae_den, v2 = ssim_acc;
#pragma unroll
    for (int off = 32; off >= 1; off >>= 1) {
        v0 += __shfl_down(v0, off);
        v1 += __shfl_down(v1, off);
        v2 += __shfl_down(v2, off);
    }
    const int wave = tid >> 6;
    const int lane = tid & 63;
    if (lane == 0) { red[wave][0] = v0; red[wave][1] = v1; red[wave][2] = v2; }
    __syncthreads();
    if (tid == 0) {
        float r0 = 0.f, r1 = 0.f, r2 = 0.f;
#pragma unroll
        for (int w = 0; w < 8; ++w) { r0 += red[w][0]; r1 += red[w][1]; r2 += red[w][2]; }
        atomicAdd(&ws[0], r0);
        atomicAdd(&ws[1], r1);
        atomicAdd(&ws[2], r2);
    }
}

__global__ void finalize_kernel(const float* __restrict__ ws, float* __restrict__ out) {
    if (threadIdx.x == 0 && blockIdx.x == 0) {
        const float mae = ws[0] / (ws[1] + 1e-8f);
        const float ssim_mean = ws[2] * (1.0f / 11943936.0f); // 4096 * 54 * 54
        out[0] = 0.5f * mae + 0.5f * (1.0f - ssim_mean);
    }
}

extern "C" void kernel_launch(void* const* d_in, const int* in_sizes, int n_in,
                              void* d_out, int out_size, void* d_ws, size_t ws_size,
                              hipStream_t stream) {
    const float* in   = (const float*)d_in[0];
    const float* outp = (const float*)d_in[1];
    const float* tgt  = (const float*)d_in[2];
    float* ws = (float*)d_ws;

    hipMemsetAsync(d_ws, 0, 3 * sizeof(float), stream);
    fused_loss_kernel<<<4096, 512, 0, stream>>>(in, outp, tgt, ws);
    finalize_kernel<<<1, 64, 0, stream>>>(ws, (float*)d_out);
}

// Round 2
// 185.778 us; speedup vs baseline: 2.5759x; 2.5759x over previous
//
#include <hip/hip_runtime.h>
#include <hip/hip_fp16.h>

// Fused WeightedMAE + Patch-SSIM loss for (8,8,512,512) fp32 inputs.
// One block per (patch, channel): 512 patches x 8 channels = 4096 blocks.
// Phase A: load 64x64 tile (x = in+out, y = tgt) into LDS fp32, fuse MAE.
// Phase B: horizontal 11-tap gaussian conv of {x,y,x^2,y^2,xy} -> fp16 LDS.
// Phase C: vertical 11-tap conv, 3row x 2col register blocks (30 acc regs,
//          no spill), 486/512 threads each own one chunk.
// Reduction: wave shuffle -> LDS -> atomicAdd to d_ws; tiny finalize kernel.
// LDS = 2*64*72*4 + 5*64*60*2 + 96 = 75.4 KB -> 2 blocks/CU (16 waves).

#define C1c 1.0e-4f
#define C2c 9.0e-4f

__global__ __launch_bounds__(512, 4)
void fused_loss_kernel(const float* __restrict__ in,
                       const float* __restrict__ outp,
                       const float* __restrict__ tgt,
                       float* __restrict__ ws) {
    __shared__ float  xt[64][72];         // cols 64..67 zeroed, 68..71 unused
    __shared__ float  yt[64][72];
    __shared__ __half Hq[5][64][60];      // horizontal conv results (54+2 used)
    __shared__ float  red[8][3];

    const int tid = threadIdx.x;
    const int pc  = blockIdx.x;           // 0..4095
    const int ch  = pc & 7;
    const int p   = pc >> 3;              // 0..511
    const int b   = p >> 6;
    const int ph  = (p >> 3) & 7;
    const int pw  = p & 7;

    // gaussian weights (float32 pipeline, matches np)
    float wgt[11];
    {
        float s = 0.0f;
#pragma unroll
        for (int j = 0; j < 11; ++j) {
            float d = (float)(j - 5);
            wgt[j] = expf(-d * d / 4.5f);
            s += wgt[j];
        }
        float invs = 1.0f / s;
#pragma unroll
        for (int j = 0; j < 11; ++j) wgt[j] *= invs;
    }

    // ---------------- Phase A: load tile + MAE ----------------
    float mae_num = 0.0f, mae_den = 0.0f;
    const size_t img_base =
        ((size_t)(b * 8 + ch) * 512 + (size_t)(ph * 64)) * 512 + (size_t)(pw * 64);

#pragma unroll
    for (int i = 0; i < 2; ++i) {
        const int pos = tid + i * 512;        // 0..1023 float4 positions
        const int r   = pos >> 4;             // 0..63
        const int c4  = (pos & 15) << 2;      // 0..60
        const size_t off = img_base + (size_t)r * 512 + (size_t)c4;
        const float4 iv = *(const float4*)(in   + off);
        const float4 ov = *(const float4*)(outp + off);
        const float4 tv = *(const float4*)(tgt  + off);
        float4 xv;
        xv.x = iv.x + ov.x; xv.y = iv.y + ov.y;
        xv.z = iv.z + ov.z; xv.w = iv.w + ov.w;
        *(float4*)&xt[r][c4] = xv;
        *(float4*)&yt[r][c4] = tv;
        // MAE: hp = tgt - in; w = |hp|>0; num += w*|out - hp|  (branchless)
        {
            float hp, w;
            hp = tv.x - iv.x; w = (fabsf(hp) > 0.0f) ? 1.0f : 0.0f;
            mae_den += w; mae_num = fmaf(w, fabsf(ov.x - hp), mae_num);
            hp = tv.y - iv.y; w = (fabsf(hp) > 0.0f) ? 1.0f : 0.0f;
            mae_den += w; mae_num = fmaf(w, fabsf(ov.y - hp), mae_num);
            hp = tv.z - iv.z; w = (fabsf(hp) > 0.0f) ? 1.0f : 0.0f;
            mae_den += w; mae_num = fmaf(w, fabsf(ov.z - hp), mae_num);
            hp = tv.w - iv.w; w = (fabsf(hp) > 0.0f) ? 1.0f : 0.0f;
            mae_den += w; mae_num = fmaf(w, fabsf(ov.w - hp), mae_num);
        }
    }
    // zero-fill padding cols 64..67
    if (tid < 64) {
        const float4 z = make_float4(0.f, 0.f, 0.f, 0.f);
        *(float4*)&xt[tid][64] = z;
        *(float4*)&yt[tid][64] = z;
    }
    __syncthreads();

    // ---------------- Phase B: horizontal conv -> fp16 Hq ----------------
    // 64 rows x 14 col-chunks (4 outputs each) = 896 chunks over 512 threads.
#pragma unroll
    for (int it = 0; it < 2; ++it) {
        const int chunk = tid + it * 512;
        if (chunk < 896) {
            const int row = chunk / 14;
            const int cc  = chunk - row * 14;
            const int c0  = cc << 2;          // 0..52
            float xs[16], ys[16];
#pragma unroll
            for (int v = 0; v < 4; ++v) {
                const float4 x4 = *(const float4*)&xt[row][c0 + 4 * v];
                const float4 y4 = *(const float4*)&yt[row][c0 + 4 * v];
                xs[4*v+0] = x4.x; xs[4*v+1] = x4.y; xs[4*v+2] = x4.z; xs[4*v+3] = x4.w;
                ys[4*v+0] = y4.x; ys[4*v+1] = y4.y; ys[4*v+2] = y4.z; ys[4*v+3] = y4.w;
            }
            float s0[4] = {0,0,0,0}, s1[4] = {0,0,0,0}, s2[4] = {0,0,0,0};
            float s3[4] = {0,0,0,0}, s4[4] = {0,0,0,0};
#pragma unroll
            for (int j = 0; j < 11; ++j) {
                const float w = wgt[j];
#pragma unroll
                for (int o = 0; o < 4; ++o) {
                    const float xv = xs[o + j];
                    const float yv = ys[o + j];
                    const float tx = w * xv;
                    const float ty = w * yv;
                    s0[o] += tx;
                    s1[o] += ty;
                    s2[o] = fmaf(tx, xv, s2[o]);
                    s3[o] = fmaf(ty, yv, s3[o]);
                    s4[o] = fmaf(tx, yv, s4[o]);
                }
            }
            *(__half2*)&Hq[0][row][c0]     = __floats2half2_rn(s0[0], s0[1]);
            *(__half2*)&Hq[0][row][c0 + 2] = __floats2half2_rn(s0[2], s0[3]);
            *(__half2*)&Hq[1][row][c0]     = __floats2half2_rn(s1[0], s1[1]);
            *(__half2*)&Hq[1][row][c0 + 2] = __floats2half2_rn(s1[2], s1[3]);
            *(__half2*)&Hq[2][row][c0]     = __floats2half2_rn(s2[0], s2[1]);
            *(__half2*)&Hq[2][row][c0 + 2] = __floats2half2_rn(s2[2], s2[3]);
            *(__half2*)&Hq[3][row][c0]     = __floats2half2_rn(s3[0], s3[1]);
            *(__half2*)&Hq[3][row][c0 + 2] = __floats2half2_rn(s3[2], s3[3]);
            *(__half2*)&Hq[4][row][c0]     = __floats2half2_rn(s4[0], s4[1]);
            *(__half2*)&Hq[4][row][c0 + 2] = __floats2half2_rn(s4[2], s4[3]);
        }
    }
    __syncthreads();

    // ---------------- Phase C: vertical conv + SSIM ----------------
    // 18 row-chunks (3 rows) x 27 col-chunks (2 cols) = 486 chunks, 1/thread.
    float ssim_acc = 0.0f;
    if (tid < 486) {
        const int vrc = tid / 27;           // 0..17
        const int cc  = tid - vrc * 27;     // 0..26
        const int c0  = cc << 1;            // 0..52
        const int vr0 = vrc * 3;            // 0..51
        float acc[3][5][2];
#pragma unroll
        for (int i = 0; i < 3; ++i)
#pragma unroll
            for (int q = 0; q < 5; ++q) {
                acc[i][q][0] = 0.0f; acc[i][q][1] = 0.0f;
            }
#pragma unroll
        for (int hr = 0; hr < 13; ++hr) {
            float h[5][2];
#pragma unroll
            for (int q = 0; q < 5; ++q) {
                const __half2 t = *(const __half2*)&Hq[q][vr0 + hr][c0];
                h[q][0] = __half2float(t.x);
                h[q][1] = __half2float(t.y);
            }
#pragma unroll
            for (int i = 0; i < 3; ++i) {
                const int j = hr - i;
                if (j >= 0 && j <= 10) {      // folds at compile time
                    const float w = wgt[j];
#pragma unroll
                    for (int q = 0; q < 5; ++q) {
                        acc[i][q][0] = fmaf(w, h[q][0], acc[i][q][0]);
                        acc[i][q][1] = fmaf(w, h[q][1], acc[i][q][1]);
                    }
                }
            }
        }
#pragma unroll
        for (int i = 0; i < 3; ++i) {
#pragma unroll
            for (int k = 0; k < 2; ++k) {
                const float mu1 = acc[i][0][k], mu2 = acc[i][1][k];
                const float sxx = acc[i][2][k], syy = acc[i][3][k], sxy = acc[i][4][k];
                const float mu1sq = mu1 * mu1;
                const float mu2sq = mu2 * mu2;
                const float mu12  = mu1 * mu2;
                const float num = (2.0f * mu12 + C1c) * (2.0f * (sxy - mu12) + C2c);
                const float den = (mu1sq + mu2sq + C1c) *
                                  ((sxx - mu1sq) + (syy - mu2sq) + C2c);
                ssim_acc += num / den;
            }
        }
    }

    // ---------------- Reduction ----------------
    float v0 = mae_num, v1 = mae_den, v2 = ssim_acc;
#pragma unroll
    for (int off = 32; off >= 1; off >>= 1) {
        v0 += __shfl_down(v0, off);
        v1 += __shfl_down(v1, off);
        v2 += __shfl_down(v2, off);
    }
    const int wave = tid >> 6;
    const int lane = tid & 63;
    if (lane == 0) { red[wave][0] = v0; red[wave][1] = v1; red[wave][2] = v2; }
    __syncthreads();
    if (tid == 0) {
        float r0 = 0.f, r1 = 0.f, r2 = 0.f;
#pragma unroll
        for (int w = 0; w < 8; ++w) { r0 += red[w][0]; r1 += red[w][1]; r2 += red[w][2]; }
        atomicAdd(&ws[0], r0);
        atomicAdd(&ws[1], r1);
        atomicAdd(&ws[2], r2);
    }
}

__global__ void finalize_kernel(const float* __restrict__ ws, float* __restrict__ out) {
    if (threadIdx.x == 0 && blockIdx.x == 0) {
        const float mae = ws[0] / (ws[1] + 1e-8f);
        const float ssim_mean = ws[2] * (1.0f / 11943936.0f); // 4096 * 54 * 54
        out[0] = 0.5f * mae + 0.5f * (1.0f - ssim_mean);
    }
}

extern "C" void kernel_launch(void* const* d_in, const int* in_sizes, int n_in,
                              void* d_out, int out_size, void* d_ws, size_t ws_size,
                              hipStream_t stream) {
    const float* in   = (const float*)d_in[0];
    const float* outp = (const float*)d_in[1];
    const float* tgt  = (const float*)d_in[2];
    float* ws = (float*)d_ws;

    hipMemsetAsync(d_ws, 0, 3 * sizeof(float), stream);
    fused_loss_kernel<<<4096, 512, 0, stream>>>(in, outp, tgt, ws);
    finalize_kernel<<<1, 64, 0, stream>>>(ws, (float*)d_out);
}